// Round 2
// baseline (1217.175 us; speedup 1.0000x reference)
//
#include <hip/hip_runtime.h>

#define DD     1024
#define HH     16
#define KVH    4
#define HDIM   64
#define NLAYER 6
#define FDIM   4096
#define VDIM   4096
#define NCODE  15
#define SS     16
#define KVDIM  256      // KVH*HDIM
#define EPSF   1e-6f
#define NBLK   256      // 1 block/CU: co-residency unconditional -> spin barrier safe

__device__ __forceinline__ float dot4(float4 a, float4 b){
  return a.x*b.x + a.y*b.y + a.z*b.z + a.w*b.w;
}
__device__ __forceinline__ float wave_sum(float v){
  #pragma unroll
  for (int o=32;o;o>>=1) v += __shfl_xor(v,o);
  return v;
}
__device__ __forceinline__ float grp16_sum(float v){
  #pragma unroll
  for (int o=8;o;o>>=1) v += __shfl_xor(v,o);
  return v;
}
__device__ __forceinline__ float grp16_max(float v){
  #pragma unroll
  for (int o=8;o;o>>=1) v = fmaxf(v, __shfl_xor(v,o));
  return v;
}

// hand-rolled grid barrier: generation-counting, agent-scope atomics + device fences.
// bar[0]=arrival counter, bar[1]=generation. Re-entrant across launches (any start gen).
__device__ __forceinline__ void gbar(unsigned* bar){
  __syncthreads();
  if (threadIdx.x == 0){
    __threadfence();   // release this block's prior stores (L2 writeback, device scope)
    unsigned g = __hip_atomic_load(bar+1, __ATOMIC_RELAXED, __HIP_MEMORY_SCOPE_AGENT);
    unsigned a = __hip_atomic_fetch_add(bar, 1u, __ATOMIC_RELAXED, __HIP_MEMORY_SCOPE_AGENT);
    if (a == (unsigned)(NBLK-1)){
      __hip_atomic_store(bar, 0u, __ATOMIC_RELAXED, __HIP_MEMORY_SCOPE_AGENT);
      __hip_atomic_fetch_add(bar+1, 1u, __ATOMIC_RELEASE, __HIP_MEMORY_SCOPE_AGENT);
    } else {
      while (__hip_atomic_load(bar+1, __ATOMIC_RELAXED, __HIP_MEMORY_SCOPE_AGENT) == g)
        __builtin_amdgcn_s_sleep(2);
    }
    __threadfence();   // acquire other blocks' stores (L2 invalidate)
  }
  __syncthreads();
}

__global__ void k_barinit(unsigned* bar){ bar[0]=0u; bar[1]=0u; }

// per-16-lane-group head rms + rope via precomputed cos/sin tables
__device__ __forceinline__ float4 rms_rope16(float4 x, const float4* nw4,
                                             const float* cosb, const float* sinb,
                                             int idx16)
{
  float ssum = grp16_sum(dot4(x,x));
  const float inv = rsqrtf(ssum*(1.0f/HDIM)+EPSF);
  float4 w = nw4[idx16];
  float x0=x.x*inv*w.x, x1=x.y*inv*w.y, x2=x.z*inv*w.z, x3=x.w*inv*w.w;
  float p0=__shfl_xor(x0,8), p1=__shfl_xor(x1,8), p2=__shfl_xor(x2,8), p3=__shfl_xor(x3,8);
  float4 c = ((const float4*)cosb)[idx16];
  float4 s = ((const float4*)sinb)[idx16];
  const float sgn = (idx16 < 8) ? -1.f : 1.f;
  float4 r;
  r.x = x0*c.x + sgn*p0*s.x;
  r.y = x1*c.y + sgn*p1*s.y;
  r.z = x2*c.z + sgn*p2*s.z;
  r.w = x3*c.w + sgn*p3*s.w;
  return r;
}

__global__ __launch_bounds__(256) void k_fused(
    const float* __restrict__ emb,   const int* __restrict__ clen,
    const float* __restrict__ kcache,const float* __restrict__ pmask,
    const float* __restrict__ umask, const float* __restrict__ vcache,
    const float* __restrict__ invf,
    const float* __restrict__ Wq,    const float* __restrict__ Wk,
    const float* __restrict__ Wv,    const float* __restrict__ Wo,
    const float* __restrict__ ln1,   const float* __restrict__ ln2,
    const float* __restrict__ qn,    const float* __restrict__ kn,
    const float* __restrict__ Wg,    const float* __restrict__ Wu,
    const float* __restrict__ Wd,    const float* __restrict__ nw,
    const float* __restrict__ lmw,
    float* __restrict__ out_logits,  float* __restrict__ out_hidden,
    float* __restrict__ out_nkc,     float* __restrict__ out_nvc,
    float* __restrict__ ws,          unsigned* __restrict__ bar)
{
  const int t = threadIdx.x, lane = t & 63, wid = t >> 6;
  const int gw = blockIdx.x*4 + wid;       // global wave id: [0,1024)

  __shared__ float xs[FDIM];               // 16 KB, reused per stage
  __shared__ float ksh[KVDIM], vsh[KVDIM];
  __shared__ float awsh[HH*SS];
  __shared__ float umsh[SS], pmsh[SS];
  __shared__ float red[4];

  float* hidden = ws;            // 1024
  float* qkv    = ws + 1024;     // 1536
  float* act    = ws + 2560;     // 4096
  float* knew   = ws + 6656;     // 1536
  float* vnew   = ws + 8192;     // 1536
  float* cosb   = ws + 9728;     // 64
  float* sinb   = ws + 9792;     // 64

  if (t < SS){ umsh[t] = umask[t]; pmsh[t] = pmask[t]; }

  // ---- init: hidden copy + rope tables (block 0) ----
  if (blockIdx.x == 0){
    ((float4*)hidden)[t] = ((const float4*)emb)[t];
    if (t < 64){
      const float f = invf[t & 31] * (float)clen[0];
      cosb[t] = cosf(f);
      sinb[t] = sinf(f);
    }
  }
  gbar(bar);

  for (int l = 0; l < NLAYER; ++l){
    const float* Wq_l = Wq + (size_t)l*HH*HDIM*DD;
    const float* Wk_l = Wk + (size_t)l*KVDIM*DD;
    const float* Wv_l = Wv + (size_t)l*KVDIM*DD;
    const float* Wo_l = Wo + (size_t)l*DD*HH*HDIM;
    const float* Wg_l = Wg + (size_t)l*FDIM*DD;
    const float* Wu_l = Wu + (size_t)l*FDIM*DD;
    const float* Wd_l = Wd + (size_t)l*DD*FDIM;
    const float* kc_l = kcache + (size_t)l*KVDIM*SS;
    const float* vc_l = vcache + (size_t)l*KVDIM*SS;

    // ========== stage 1: rms(ln1) + QKV matvec (2 rows/wave, 8 loads in flight) ==========
    {
      float4 hv = ((const float4*)hidden)[t];
      float ssum = wave_sum(dot4(hv,hv));
      if (lane==0) red[wid] = ssum;
      __syncthreads();
      const float inv = rsqrtf((red[0]+red[1]+red[2]+red[3])*(1.0f/DD) + EPSF);
      float4 lw = ((const float4*)(ln1 + l*DD))[t];
      float4 xv; xv.x=hv.x*inv*lw.x; xv.y=hv.y*inv*lw.y; xv.z=hv.z*inv*lw.z; xv.w=hv.w*inv*lw.w;
      ((float4*)xs)[t] = xv;
      __syncthreads();
      const float4* x4 = (const float4*)xs;
      // rowA = gw (always a Wq row, 0..1023); rowB = 1024+gw (k/v rows, gw<512)
      const float4* wa = (const float4*)(Wq_l + (size_t)gw*DD);
      if (gw < 512){
        const float* Wrow = (gw < 256) ? (Wk_l + (size_t)gw*DD) : (Wv_l + (size_t)(gw-256)*DD);
        const float4* wb = (const float4*)Wrow;
        float4 a0=wa[lane], a1=wa[64+lane], a2=wa[128+lane], a3=wa[192+lane];
        float4 b0=wb[lane], b1=wb[64+lane], b2=wb[128+lane], b3=wb[192+lane];
        float accA = dot4(a0,x4[lane])+dot4(a1,x4[64+lane])+dot4(a2,x4[128+lane])+dot4(a3,x4[192+lane]);
        float accB = dot4(b0,x4[lane])+dot4(b1,x4[64+lane])+dot4(b2,x4[128+lane])+dot4(b3,x4[192+lane]);
        accA = wave_sum(accA); accB = wave_sum(accB);
        if (lane==0){ qkv[gw] = accA; qkv[1024+gw] = accB; }
      } else {
        float4 a0=wa[lane], a1=wa[64+lane], a2=wa[128+lane], a3=wa[192+lane];
        float accA = dot4(a0,x4[lane])+dot4(a1,x4[64+lane])+dot4(a2,x4[128+lane])+dot4(a3,x4[192+lane]);
        accA = wave_sum(accA);
        if (lane==0) qkv[gw] = accA;
      }
    }
    gbar(bar);

    // ========== stage 2: (redundant per-block) attention + Wo matvec ==========
    {
      const int idx16 = t & 15;
      // q: rms + rope -> xs[0..1023]
      {
        float4 q = ((const float4*)qkv)[t];
        float4 r = rms_rope16(q, (const float4*)(qn + l*HDIM), cosb, sinb, idx16);
        ((float4*)xs)[t] = r;
      }
      // k: rms + rope -> ksh ; v passthrough -> vsh (wave 0 only)
      if (t < 64){
        float4 k = ((const float4*)(qkv+1024))[t];
        float4 r = rms_rope16(k, (const float4*)(kn + l*HDIM), cosb, sinb, idx16);
        ((float4*)ksh)[t] = r;
        float4 v = ((const float4*)(qkv+1280))[t];
        ((float4*)vsh)[t] = v;
        if (blockIdx.x == 0){
          ((float4*)(knew + l*KVDIM))[t] = r;
          ((float4*)(vnew + l*KVDIM))[t] = v;
        }
      }
      __syncthreads();
      // scores + softmax: thread = (head h, pos s)
      {
        const int h = t>>4, s = t&15, kvh = h>>2;
        const float um = umsh[s], pm = pmsh[s];
        const float* kcol = kc_l + (size_t)(kvh*HDIM)*SS + s;
        const float* ksrc = ksh + kvh*HDIM;
        const float* qv   = xs + h*HDIM;
        float dot = 0.f;
        #pragma unroll
        for (int d=0; d<HDIM; d++){
          float kc = kcol[d*SS]*(1.f-um) + ksrc[d]*um;
          dot += qv[d]*kc;
        }
        const float sc = dot*0.125f + pm;
        const float mx = grp16_max(sc);
        const float e  = expf(sc-mx);
        const float sm = grp16_sum(e);
        awsh[t] = e/sm;
      }
      __syncthreads();
      // ao[h][d] -> xs[1024..2047]
      {
        const int h = t>>4, i16 = t&15, kvh = h>>2;
        const int cb = kvh*HDIM + i16*4;
        float a0=0,a1=0,a2=0,a3=0;
        #pragma unroll
        for (int s=0;s<SS;s++){
          const float aw = awsh[h*16+s];
          const float um = umsh[s];
          a0 += aw*(vc_l[(size_t)(cb+0)*SS+s]*(1.f-um)+vsh[cb+0]*um);
          a1 += aw*(vc_l[(size_t)(cb+1)*SS+s]*(1.f-um)+vsh[cb+1]*um);
          a2 += aw*(vc_l[(size_t)(cb+2)*SS+s]*(1.f-um)+vsh[cb+2]*um);
          a3 += aw*(vc_l[(size_t)(cb+3)*SS+s]*(1.f-um)+vsh[cb+3]*um);
        }
        ((float4*)(xs+1024))[t] = make_float4(a0,a1,a2,a3);
      }
      __syncthreads();
      // Wo matvec + residual (1 row/wave, 1024 rows exactly)
      {
        const float4* w4 = (const float4*)(Wo_l + (size_t)gw*DD);
        const float4* x4 = (const float4*)(xs+1024);
        float4 w0=w4[lane], w1=w4[64+lane], w2=w4[128+lane], w3=w4[192+lane];
        float acc = dot4(w0,x4[lane])+dot4(w1,x4[64+lane])+dot4(w2,x4[128+lane])+dot4(w3,x4[192+lane]);
        acc = wave_sum(acc);
        if (lane==0) hidden[gw] += acc;
      }
    }
    gbar(bar);

    // ========== stage 3: rms(ln2) + gate/up (2 rows x 2 mats = 16 loads in flight) ==========
    {
      float4 hv = ((const float4*)hidden)[t];
      float ssum = wave_sum(dot4(hv,hv));
      if (lane==0) red[wid] = ssum;
      __syncthreads();
      const float inv = rsqrtf((red[0]+red[1]+red[2]+red[3])*(1.0f/DD) + EPSF);
      float4 lw = ((const float4*)(ln2 + l*DD))[t];
      float4 xv; xv.x=hv.x*inv*lw.x; xv.y=hv.y*inv*lw.y; xv.z=hv.z*inv*lw.z; xv.w=hv.w*inv*lw.w;
      ((float4*)xs)[t] = xv;
      __syncthreads();
      const float4* x4 = (const float4*)xs;
      #pragma unroll
      for (int half=0; half<2; half++){
        const int r0 = gw + half*2048;
        const int r1 = r0 + 1024;
        const float4* g0 = (const float4*)(Wg_l + (size_t)r0*DD);
        const float4* u0 = (const float4*)(Wu_l + (size_t)r0*DD);
        const float4* g1 = (const float4*)(Wg_l + (size_t)r1*DD);
        const float4* u1 = (const float4*)(Wu_l + (size_t)r1*DD);
        float4 wg0[4], wu0[4], wg1[4], wu1[4];
        #pragma unroll
        for (int j=0;j<4;j++){
          wg0[j]=g0[j*64+lane]; wu0[j]=u0[j*64+lane];
          wg1[j]=g1[j*64+lane]; wu1[j]=u1[j*64+lane];
        }
        float ag0=0,au0=0,ag1=0,au1=0;
        #pragma unroll
        for (int j=0;j<4;j++){
          float4 x = x4[j*64+lane];
          ag0+=dot4(wg0[j],x); au0+=dot4(wu0[j],x);
          ag1+=dot4(wg1[j],x); au1+=dot4(wu1[j],x);
        }
        ag0=wave_sum(ag0); au0=wave_sum(au0); ag1=wave_sum(ag1); au1=wave_sum(au1);
        if (lane==0){
          act[r0] = ag0/(1.f+expf(-ag0))*au0;
          act[r1] = ag1/(1.f+expf(-ag1))*au1;
        }
      }
    }
    gbar(bar);

    // ========== stage 4: Wdown matvec + residual (16 loads in flight) ==========
    {
      #pragma unroll
      for (int j=0;j<4;j++) ((float4*)xs)[j*256+t] = ((const float4*)act)[j*256+t];
      __syncthreads();
      const float4* w4 = (const float4*)(Wd_l + (size_t)gw*FDIM);
      const float4* x4 = (const float4*)xs;
      float4 wv[16];
      #pragma unroll
      for (int j=0;j<16;j++) wv[j] = w4[j*64+lane];
      float acc = 0.f;
      #pragma unroll
      for (int j=0;j<16;j++) acc += dot4(wv[j], x4[j*64+lane]);
      acc = wave_sum(acc);
      if (lane==0) hidden[gw] += acc;
    }
    gbar(bar);
  } // layers

  // ====== final: redundant rms(norm_w) + lm_head (4 rows/wave) + cache assembly ======
  {
    float4 hv = ((const float4*)hidden)[t];
    float ssum = wave_sum(dot4(hv,hv));
    if (lane==0) red[wid] = ssum;
    __syncthreads();
    const float inv = rsqrtf((red[0]+red[1]+red[2]+red[3])*(1.0f/DD) + EPSF);
    float4 w = ((const float4*)nw)[t];
    float4 nv; nv.x=hv.x*inv*w.x; nv.y=hv.y*inv*w.y; nv.z=hv.z*inv*w.z; nv.w=hv.w*inv*w.w;
    ((float4*)xs)[t] = nv;
    if (blockIdx.x == 0) ((float4*)out_hidden)[t] = nv;
    __syncthreads();
    const float4* x4 = (const float4*)xs;
    // lm_head: 61440 rows = 15 iters x (4 rows/wave x 1024 waves)
    for (int it=0; it<15; ++it){
      const int r0 = it*4096 + gw;
      const float4* p0 = (const float4*)(lmw + (size_t)r0*DD);
      const float4* p1 = (const float4*)(lmw + (size_t)(r0+1024)*DD);
      const float4* p2 = (const float4*)(lmw + (size_t)(r0+2048)*DD);
      const float4* p3 = (const float4*)(lmw + (size_t)(r0+3072)*DD);
      float4 w0[4],w1[4],w2[4],w3[4];
      #pragma unroll
      for (int j=0;j<4;j++){ w0[j]=p0[j*64+lane]; w1[j]=p1[j*64+lane]; w2[j]=p2[j*64+lane]; w3[j]=p3[j*64+lane]; }
      float a0=0,a1=0,a2=0,a3=0;
      #pragma unroll
      for (int j=0;j<4;j++){
        float4 x = x4[j*64+lane];
        a0+=dot4(w0[j],x); a1+=dot4(w1[j],x); a2+=dot4(w2[j],x); a3+=dot4(w3[j],x);
      }
      a0=wave_sum(a0); a1=wave_sum(a1); a2=wave_sum(a2); a3=wave_sum(a3);
      if (lane==0){
        out_logits[r0]      = a0;
        out_logits[r0+1024] = a1;
        out_logits[r0+2048] = a2;
        out_logits[r0+3072] = a3;
      }
    }
    // nkc/nvc assembly (blocks 0..95 cover 24576 elems in one pass)
    for (int j = blockIdx.x*256 + t; j < NLAYER*KVDIM*SS; j += NBLK*256){
      const int s = j & 15, c = j >> 4;
      const float um = umsh[s];
      out_nkc[j] = kcache[j]*(1.f-um) + knew[c]*um;
      out_nvc[j] = vcache[j]*(1.f-um) + vnew[c]*um;
    }
  }
}

extern "C" void kernel_launch(void* const* d_in, const int* in_sizes, int n_in,
                              void* d_out, int out_size, void* d_ws, size_t ws_size,
                              hipStream_t stream)
{
  const float* emb    = (const float*)d_in[0];
  const int*   clen   = (const int*)  d_in[1];
  const float* kcache = (const float*)d_in[2];
  const float* pmask  = (const float*)d_in[3];
  const float* umask  = (const float*)d_in[4];
  const float* vcache = (const float*)d_in[5];
  const float* invf   = (const float*)d_in[6];
  const float* Wq     = (const float*)d_in[7];
  const float* Wk     = (const float*)d_in[8];
  const float* Wv     = (const float*)d_in[9];
  const float* Wo     = (const float*)d_in[10];
  const float* ln1    = (const float*)d_in[11];
  const float* ln2    = (const float*)d_in[12];
  const float* qn     = (const float*)d_in[13];
  const float* kn     = (const float*)d_in[14];
  const float* Wg     = (const float*)d_in[15];
  const float* Wu     = (const float*)d_in[16];
  const float* Wd     = (const float*)d_in[17];
  const float* nw     = (const float*)d_in[18];
  const float* lmw    = (const float*)d_in[19];
  float* out = (float*)d_out;
  float* ws  = (float*)d_ws;

  float* out_logits = out;
  float* out_hidden = out + NCODE*VDIM;
  float* out_nkc    = out_hidden + DD;
  float* out_nvc    = out_nkc + NLAYER*KVDIM*SS;

  unsigned* bar = (unsigned*)(ws + 16384);

  k_barinit<<<1,1,0,stream>>>(bar);
  k_fused<<<NBLK,256,0,stream>>>(emb, clen, kcache, pmask, umask, vcache, invf,
                                 Wq, Wk, Wv, Wo, ln1, ln2, qn, kn, Wg, Wu, Wd, nw, lmw,
                                 out_logits, out_hidden, out_nkc, out_nvc, ws, bar);
}

// Round 3
// 866.953 us; speedup vs baseline: 1.4040x; 1.4040x over previous
//
#include <hip/hip_runtime.h>

#define DD     1024
#define HH     16
#define KVH    4
#define HDIM   64
#define NLAYER 6
#define FDIM   4096
#define VDIM   4096
#define NCODE  15
#define SS     16
#define KVDIM  256      // KVH*HDIM
#define EPSF   1e-6f
#define NBLK   256      // 1 block/CU: co-residency unconditional -> spin barrier safe

__device__ __forceinline__ float dot4(float4 a, float4 b){
  return a.x*b.x + a.y*b.y + a.z*b.z + a.w*b.w;
}
__device__ __forceinline__ float wave_sum(float v){
  #pragma unroll
  for (int o=32;o;o>>=1) v += __shfl_xor(v,o);
  return v;
}
__device__ __forceinline__ float grp16_sum(float v){
  #pragma unroll
  for (int o=8;o;o>>=1) v += __shfl_xor(v,o);
  return v;
}
__device__ __forceinline__ float grp16_max(float v){
  #pragma unroll
  for (int o=8;o;o>>=1) v = fmaxf(v, __shfl_xor(v,o));
  return v;
}

// Distributed-flag grid barrier: NO atomic RMW (the round-2 version's single
// fetch_add line serialized 256 cross-XCD RMWs ~26us/barrier).
// flags[0..255]  : per-block arrival words (store-only, parallel)
// flags[320]     : release word (block 0 broadcasts generation)
__device__ __forceinline__ void gbar(unsigned* flags, unsigned gen){
  __syncthreads();                      // drains vmcnt: all block stores are in L2
  if (threadIdx.x == 0){
    __threadfence();                    // agent release: L2 writeback -> device-visible
    __hip_atomic_store(flags + blockIdx.x, gen, __ATOMIC_RELAXED, __HIP_MEMORY_SCOPE_AGENT);
  }
  if (blockIdx.x == 0){
    if (threadIdx.x < 64){
      const int i0 = threadIdx.x, i1 = i0+64, i2 = i0+128, i3 = i0+192;
      for (;;){
        unsigned f0 = __hip_atomic_load(flags+i0, __ATOMIC_RELAXED, __HIP_MEMORY_SCOPE_AGENT);
        unsigned f1 = __hip_atomic_load(flags+i1, __ATOMIC_RELAXED, __HIP_MEMORY_SCOPE_AGENT);
        unsigned f2 = __hip_atomic_load(flags+i2, __ATOMIC_RELAXED, __HIP_MEMORY_SCOPE_AGENT);
        unsigned f3 = __hip_atomic_load(flags+i3, __ATOMIC_RELAXED, __HIP_MEMORY_SCOPE_AGENT);
        if (f0==gen && f1==gen && f2==gen && f3==gen) break;
        __builtin_amdgcn_s_sleep(2);
      }
    }
    __syncthreads();
    if (threadIdx.x == 0){
      __threadfence();                  // full fence: also acquires others' data for block 0
      __hip_atomic_store(flags + 320, gen, __ATOMIC_RELAXED, __HIP_MEMORY_SCOPE_AGENT);
    }
  } else {
    if (threadIdx.x == 0){
      while (__hip_atomic_load(flags+320, __ATOMIC_RELAXED, __HIP_MEMORY_SCOPE_AGENT) != gen)
        __builtin_amdgcn_s_sleep(2);
      __threadfence();                  // acquire: invalidate L1/L2 so fresh data is seen
    }
  }
  __syncthreads();
}

__global__ void k_barinit(unsigned* flags){
  flags[threadIdx.x] = 0u;              // 512 threads cover flags+release
}

// per-16-lane-group head rms + rope via precomputed cos/sin tables
__device__ __forceinline__ float4 rms_rope16(float4 x, const float4* nw4,
                                             const float* cosb, const float* sinb,
                                             int idx16)
{
  float ssum = grp16_sum(dot4(x,x));
  const float inv = rsqrtf(ssum*(1.0f/HDIM)+EPSF);
  float4 w = nw4[idx16];
  float x0=x.x*inv*w.x, x1=x.y*inv*w.y, x2=x.z*inv*w.z, x3=x.w*inv*w.w;
  float p0=__shfl_xor(x0,8), p1=__shfl_xor(x1,8), p2=__shfl_xor(x2,8), p3=__shfl_xor(x3,8);
  float4 c = ((const float4*)cosb)[idx16];
  float4 s = ((const float4*)sinb)[idx16];
  const float sgn = (idx16 < 8) ? -1.f : 1.f;
  float4 r;
  r.x = x0*c.x + sgn*p0*s.x;
  r.y = x1*c.y + sgn*p1*s.y;
  r.z = x2*c.z + sgn*p2*s.z;
  r.w = x3*c.w + sgn*p3*s.w;
  return r;
}

__global__ __launch_bounds__(256) void k_fused(
    const float* __restrict__ emb,   const int* __restrict__ clen,
    const float* __restrict__ kcache,const float* __restrict__ pmask,
    const float* __restrict__ umask, const float* __restrict__ vcache,
    const float* __restrict__ invf,
    const float* __restrict__ Wq,    const float* __restrict__ Wk,
    const float* __restrict__ Wv,    const float* __restrict__ Wo,
    const float* __restrict__ ln1,   const float* __restrict__ ln2,
    const float* __restrict__ qn,    const float* __restrict__ kn,
    const float* __restrict__ Wg,    const float* __restrict__ Wu,
    const float* __restrict__ Wd,    const float* __restrict__ nw,
    const float* __restrict__ lmw,
    float* __restrict__ out_logits,  float* __restrict__ out_hidden,
    float* __restrict__ out_nkc,     float* __restrict__ out_nvc,
    float* __restrict__ ws,          unsigned* __restrict__ bar)
{
  const int t = threadIdx.x, lane = t & 63, wid = t >> 6;
  const int gw = blockIdx.x*4 + wid;       // global wave id: [0,1024)
  unsigned gen = 0;

  __shared__ float xs[FDIM];               // 16 KB, reused per stage
  __shared__ float ksh[KVDIM], vsh[KVDIM];
  __shared__ float awsh[HH*SS];
  __shared__ float umsh[SS], pmsh[SS];
  __shared__ float red[4];

  float* hidden = ws;            // 1024
  float* qkv    = ws + 1024;     // 1536
  float* act    = ws + 2560;     // 4096
  float* knew   = ws + 6656;     // 1536
  float* vnew   = ws + 8192;     // 1536
  float* cosb   = ws + 9728;     // 64
  float* sinb   = ws + 9792;     // 64

  if (t < SS){ umsh[t] = umask[t]; pmsh[t] = pmask[t]; }

  // ---- init: hidden copy + rope tables (block 0) ----
  if (blockIdx.x == 0){
    ((float4*)hidden)[t] = ((const float4*)emb)[t];
    if (t < 64){
      const float f = invf[t & 31] * (float)clen[0];
      cosb[t] = cosf(f);
      sinb[t] = sinf(f);
    }
  }
  gbar(bar, ++gen);

  for (int l = 0; l < NLAYER; ++l){
    const float* Wq_l = Wq + (size_t)l*HH*HDIM*DD;
    const float* Wk_l = Wk + (size_t)l*KVDIM*DD;
    const float* Wv_l = Wv + (size_t)l*KVDIM*DD;
    const float* Wo_l = Wo + (size_t)l*DD*HH*HDIM;
    const float* Wg_l = Wg + (size_t)l*FDIM*DD;
    const float* Wu_l = Wu + (size_t)l*FDIM*DD;
    const float* Wd_l = Wd + (size_t)l*DD*FDIM;
    const float* kc_l = kcache + (size_t)l*KVDIM*SS;
    const float* vc_l = vcache + (size_t)l*KVDIM*SS;

    // ========== stage 1: rms(ln1) + QKV matvec (2 rows/wave, 8 loads in flight) ==========
    {
      float4 hv = ((const float4*)hidden)[t];
      float ssum = wave_sum(dot4(hv,hv));
      if (lane==0) red[wid] = ssum;
      __syncthreads();
      const float inv = rsqrtf((red[0]+red[1]+red[2]+red[3])*(1.0f/DD) + EPSF);
      float4 lw = ((const float4*)(ln1 + l*DD))[t];
      float4 xv; xv.x=hv.x*inv*lw.x; xv.y=hv.y*inv*lw.y; xv.z=hv.z*inv*lw.z; xv.w=hv.w*inv*lw.w;
      ((float4*)xs)[t] = xv;
      __syncthreads();
      const float4* x4 = (const float4*)xs;
      const float4* wa = (const float4*)(Wq_l + (size_t)gw*DD);
      if (gw < 512){
        const float* Wrow = (gw < 256) ? (Wk_l + (size_t)gw*DD) : (Wv_l + (size_t)(gw-256)*DD);
        const float4* wb = (const float4*)Wrow;
        float4 a0=wa[lane], a1=wa[64+lane], a2=wa[128+lane], a3=wa[192+lane];
        float4 b0=wb[lane], b1=wb[64+lane], b2=wb[128+lane], b3=wb[192+lane];
        float accA = dot4(a0,x4[lane])+dot4(a1,x4[64+lane])+dot4(a2,x4[128+lane])+dot4(a3,x4[192+lane]);
        float accB = dot4(b0,x4[lane])+dot4(b1,x4[64+lane])+dot4(b2,x4[128+lane])+dot4(b3,x4[192+lane]);
        accA = wave_sum(accA); accB = wave_sum(accB);
        if (lane==0){ qkv[gw] = accA; qkv[1024+gw] = accB; }
      } else {
        float4 a0=wa[lane], a1=wa[64+lane], a2=wa[128+lane], a3=wa[192+lane];
        float accA = dot4(a0,x4[lane])+dot4(a1,x4[64+lane])+dot4(a2,x4[128+lane])+dot4(a3,x4[192+lane]);
        accA = wave_sum(accA);
        if (lane==0) qkv[gw] = accA;
      }
    }
    gbar(bar, ++gen);

    // ========== stage 2: (redundant per-block) attention + Wo matvec ==========
    {
      const int idx16 = t & 15;
      {
        float4 q = ((const float4*)qkv)[t];
        float4 r = rms_rope16(q, (const float4*)(qn + l*HDIM), cosb, sinb, idx16);
        ((float4*)xs)[t] = r;
      }
      if (t < 64){
        float4 k = ((const float4*)(qkv+1024))[t];
        float4 r = rms_rope16(k, (const float4*)(kn + l*HDIM), cosb, sinb, idx16);
        ((float4*)ksh)[t] = r;
        float4 v = ((const float4*)(qkv+1280))[t];
        ((float4*)vsh)[t] = v;
        if (blockIdx.x == 0){
          ((float4*)(knew + l*KVDIM))[t] = r;
          ((float4*)(vnew + l*KVDIM))[t] = v;
        }
      }
      __syncthreads();
      {
        const int h = t>>4, s = t&15, kvh = h>>2;
        const float um = umsh[s], pm = pmsh[s];
        const float* kcol = kc_l + (size_t)(kvh*HDIM)*SS + s;
        const float* ksrc = ksh + kvh*HDIM;
        const float* qv   = xs + h*HDIM;
        float dot = 0.f;
        #pragma unroll
        for (int d=0; d<HDIM; d++){
          float kc = kcol[d*SS]*(1.f-um) + ksrc[d]*um;
          dot += qv[d]*kc;
        }
        const float sc = dot*0.125f + pm;
        const float mx = grp16_max(sc);
        const float e  = expf(sc-mx);
        const float sm = grp16_sum(e);
        awsh[t] = e/sm;
      }
      __syncthreads();
      {
        const int h = t>>4, i16 = t&15, kvh = h>>2;
        const int cb = kvh*HDIM + i16*4;
        float a0=0,a1=0,a2=0,a3=0;
        #pragma unroll
        for (int s=0;s<SS;s++){
          const float aw = awsh[h*16+s];
          const float um = umsh[s];
          a0 += aw*(vc_l[(size_t)(cb+0)*SS+s]*(1.f-um)+vsh[cb+0]*um);
          a1 += aw*(vc_l[(size_t)(cb+1)*SS+s]*(1.f-um)+vsh[cb+1]*um);
          a2 += aw*(vc_l[(size_t)(cb+2)*SS+s]*(1.f-um)+vsh[cb+2]*um);
          a3 += aw*(vc_l[(size_t)(cb+3)*SS+s]*(1.f-um)+vsh[cb+3]*um);
        }
        ((float4*)(xs+1024))[t] = make_float4(a0,a1,a2,a3);
      }
      __syncthreads();
      {
        const float4* w4 = (const float4*)(Wo_l + (size_t)gw*DD);
        const float4* x4 = (const float4*)(xs+1024);
        float4 w0=w4[lane], w1=w4[64+lane], w2=w4[128+lane], w3=w4[192+lane];
        float acc = dot4(w0,x4[lane])+dot4(w1,x4[64+lane])+dot4(w2,x4[128+lane])+dot4(w3,x4[192+lane]);
        acc = wave_sum(acc);
        if (lane==0) hidden[gw] += acc;
      }
    }
    gbar(bar, ++gen);

    // ========== stage 3: rms(ln2) + gate/up (2 rows x 2 mats = 16 loads in flight) ==========
    {
      float4 hv = ((const float4*)hidden)[t];
      float ssum = wave_sum(dot4(hv,hv));
      if (lane==0) red[wid] = ssum;
      __syncthreads();
      const float inv = rsqrtf((red[0]+red[1]+red[2]+red[3])*(1.0f/DD) + EPSF);
      float4 lw = ((const float4*)(ln2 + l*DD))[t];
      float4 xv; xv.x=hv.x*inv*lw.x; xv.y=hv.y*inv*lw.y; xv.z=hv.z*inv*lw.z; xv.w=hv.w*inv*lw.w;
      ((float4*)xs)[t] = xv;
      __syncthreads();
      const float4* x4 = (const float4*)xs;
      #pragma unroll
      for (int half=0; half<2; half++){
        const int r0 = gw + half*2048;
        const int r1 = r0 + 1024;
        const float4* g0 = (const float4*)(Wg_l + (size_t)r0*DD);
        const float4* u0 = (const float4*)(Wu_l + (size_t)r0*DD);
        const float4* g1 = (const float4*)(Wg_l + (size_t)r1*DD);
        const float4* u1 = (const float4*)(Wu_l + (size_t)r1*DD);
        float4 wg0[4], wu0[4], wg1[4], wu1[4];
        #pragma unroll
        for (int j=0;j<4;j++){
          wg0[j]=g0[j*64+lane]; wu0[j]=u0[j*64+lane];
          wg1[j]=g1[j*64+lane]; wu1[j]=u1[j*64+lane];
        }
        float ag0=0,au0=0,ag1=0,au1=0;
        #pragma unroll
        for (int j=0;j<4;j++){
          float4 x = x4[j*64+lane];
          ag0+=dot4(wg0[j],x); au0+=dot4(wu0[j],x);
          ag1+=dot4(wg1[j],x); au1+=dot4(wu1[j],x);
        }
        ag0=wave_sum(ag0); au0=wave_sum(au0); ag1=wave_sum(ag1); au1=wave_sum(au1);
        if (lane==0){
          act[r0] = ag0/(1.f+expf(-ag0))*au0;
          act[r1] = ag1/(1.f+expf(-ag1))*au1;
        }
      }
    }
    gbar(bar, ++gen);

    // ========== stage 4: Wdown matvec + residual (16 loads in flight) ==========
    {
      #pragma unroll
      for (int j=0;j<4;j++) ((float4*)xs)[j*256+t] = ((const float4*)act)[j*256+t];
      __syncthreads();
      const float4* w4 = (const float4*)(Wd_l + (size_t)gw*FDIM);
      const float4* x4 = (const float4*)xs;
      float4 wv[16];
      #pragma unroll
      for (int j=0;j<16;j++) wv[j] = w4[j*64+lane];
      float acc = 0.f;
      #pragma unroll
      for (int j=0;j<16;j++) acc += dot4(wv[j], x4[j*64+lane]);
      acc = wave_sum(acc);
      if (lane==0) hidden[gw] += acc;
    }
    gbar(bar, ++gen);
  } // layers

  // ====== final: redundant rms(norm_w) + lm_head (4 rows/wave) + cache assembly ======
  {
    float4 hv = ((const float4*)hidden)[t];
    float ssum = wave_sum(dot4(hv,hv));
    if (lane==0) red[wid] = ssum;
    __syncthreads();
    const float inv = rsqrtf((red[0]+red[1]+red[2]+red[3])*(1.0f/DD) + EPSF);
    float4 w = ((const float4*)nw)[t];
    float4 nv; nv.x=hv.x*inv*w.x; nv.y=hv.y*inv*w.y; nv.z=hv.z*inv*w.z; nv.w=hv.w*inv*w.w;
    ((float4*)xs)[t] = nv;
    if (blockIdx.x == 0) ((float4*)out_hidden)[t] = nv;
    __syncthreads();
    const float4* x4 = (const float4*)xs;
    for (int it=0; it<15; ++it){
      const int r0 = it*4096 + gw;
      const float4* p0 = (const float4*)(lmw + (size_t)r0*DD);
      const float4* p1 = (const float4*)(lmw + (size_t)(r0+1024)*DD);
      const float4* p2 = (const float4*)(lmw + (size_t)(r0+2048)*DD);
      const float4* p3 = (const float4*)(lmw + (size_t)(r0+3072)*DD);
      float4 w0[4],w1[4],w2[4],w3[4];
      #pragma unroll
      for (int j=0;j<4;j++){ w0[j]=p0[j*64+lane]; w1[j]=p1[j*64+lane]; w2[j]=p2[j*64+lane]; w3[j]=p3[j*64+lane]; }
      float a0=0,a1=0,a2=0,a3=0;
      #pragma unroll
      for (int j=0;j<4;j++){
        float4 x = x4[j*64+lane];
        a0+=dot4(w0[j],x); a1+=dot4(w1[j],x); a2+=dot4(w2[j],x); a3+=dot4(w3[j],x);
      }
      a0=wave_sum(a0); a1=wave_sum(a1); a2=wave_sum(a2); a3=wave_sum(a3);
      if (lane==0){
        out_logits[r0]      = a0;
        out_logits[r0+1024] = a1;
        out_logits[r0+2048] = a2;
        out_logits[r0+3072] = a3;
      }
    }
    for (int j = blockIdx.x*256 + t; j < NLAYER*KVDIM*SS; j += NBLK*256){
      const int s = j & 15, c = j >> 4;
      const float um = umsh[s];
      out_nkc[j] = kcache[j]*(1.f-um) + knew[c]*um;
      out_nvc[j] = vcache[j]*(1.f-um) + vnew[c]*um;
    }
  }
}

extern "C" void kernel_launch(void* const* d_in, const int* in_sizes, int n_in,
                              void* d_out, int out_size, void* d_ws, size_t ws_size,
                              hipStream_t stream)
{
  const float* emb    = (const float*)d_in[0];
  const int*   clen   = (const int*)  d_in[1];
  const float* kcache = (const float*)d_in[2];
  const float* pmask  = (const float*)d_in[3];
  const float* umask  = (const float*)d_in[4];
  const float* vcache = (const float*)d_in[5];
  const float* invf   = (const float*)d_in[6];
  const float* Wq     = (const float*)d_in[7];
  const float* Wk     = (const float*)d_in[8];
  const float* Wv     = (const float*)d_in[9];
  const float* Wo     = (const float*)d_in[10];
  const float* ln1    = (const float*)d_in[11];
  const float* ln2    = (const float*)d_in[12];
  const float* qn     = (const float*)d_in[13];
  const float* kn     = (const float*)d_in[14];
  const float* Wg     = (const float*)d_in[15];
  const float* Wu     = (const float*)d_in[16];
  const float* Wd     = (const float*)d_in[17];
  const float* nw     = (const float*)d_in[18];
  const float* lmw    = (const float*)d_in[19];
  float* out = (float*)d_out;
  float* ws  = (float*)d_ws;

  float* out_logits = out;
  float* out_hidden = out + NCODE*VDIM;
  float* out_nkc    = out_hidden + DD;
  float* out_nvc    = out_nkc + NLAYER*KVDIM*SS;

  unsigned* bar = (unsigned*)(ws + 16384);

  k_barinit<<<1,512,0,stream>>>(bar);
  k_fused<<<NBLK,256,0,stream>>>(emb, clen, kcache, pmask, umask, vcache, invf,
                                 Wq, Wk, Wv, Wo, ln1, ln2, qn, kn, Wg, Wu, Wd, nw, lmw,
                                 out_logits, out_hidden, out_nkc, out_nvc, ws, bar);
}